// Round 1
// baseline (3050.201 us; speedup 1.0000x reference)
//
#include <hip/hip_runtime.h>
#include <math.h>

#define EMBED   768
#define NHEADS  12
#define HD      64
#define BATCH   16
#define SEQ     1024
#define ATTN_SCALE 0.125f   // 1/sqrt(64)

// ---------------------------------------------------------------------------
// GEMM 128x128x8 fp32, 256 threads, 8x8 microtile per thread.
// A: [M,K] row-major. B: [K,N] row-major. C scatter differs per kernel.
// ---------------------------------------------------------------------------

__global__ __launch_bounds__(256)
void qkv_gemm(const float* __restrict__ X, const float* __restrict__ W,
              const float* __restrict__ bias,
              float* __restrict__ qws, float* __restrict__ kws,
              float* __restrict__ vws)
{
    const int K  = EMBED;      // 768
    const int Nn = 3 * EMBED;  // 2304
    const int bm = blockIdx.y; // 0..127
    const int bn = blockIdx.x; // 0..17
    const int t  = threadIdx.x;

    __shared__ float As[8][128];
    __shared__ float Bs[8][128];

    float acc[8][8];
#pragma unroll
    for (int i = 0; i < 8; i++)
#pragma unroll
        for (int j = 0; j < 8; j++) acc[i][j] = 0.f;

    const int rowA = bm * 128 + (t >> 1);
    const int kA   = (t & 1) * 4;
    const int rowB = t >> 5;
    const int colB = bn * 128 + (t & 31) * 4;
    const int ty = t >> 4, tx = t & 15;

    for (int k0 = 0; k0 < K; k0 += 8) {
        float4 a = *(const float4*)&X[(size_t)rowA * K + k0 + kA];
        float4 b = *(const float4*)&W[(size_t)(k0 + rowB) * Nn + colB];
        As[kA + 0][t >> 1] = a.x;
        As[kA + 1][t >> 1] = a.y;
        As[kA + 2][t >> 1] = a.z;
        As[kA + 3][t >> 1] = a.w;
        *(float4*)&Bs[rowB][(t & 31) * 4] = b;
        __syncthreads();
#pragma unroll
        for (int kk = 0; kk < 8; kk++) {
            float4 a0 = *(const float4*)&As[kk][ty * 8];
            float4 a1 = *(const float4*)&As[kk][ty * 8 + 4];
            float4 b0 = *(const float4*)&Bs[kk][tx * 8];
            float4 b1 = *(const float4*)&Bs[kk][tx * 8 + 4];
            float av[8] = {a0.x, a0.y, a0.z, a0.w, a1.x, a1.y, a1.z, a1.w};
            float bv[8] = {b0.x, b0.y, b0.z, b0.w, b1.x, b1.y, b1.z, b1.w};
#pragma unroll
            for (int i = 0; i < 8; i++)
#pragma unroll
                for (int j = 0; j < 8; j++) acc[i][j] = fmaf(av[i], bv[j], acc[i][j]);
        }
        __syncthreads();
    }

    // epilogue: bias + scatter into q/k/v [B][H][N][HD]
#pragma unroll
    for (int i = 0; i < 8; i++) {
        int rr = bm * 128 + ty * 8 + i;
        int bb = rr >> 10;       // /1024
        int nn = rr & 1023;
#pragma unroll
        for (int j = 0; j < 8; j++) {
            int c = bn * 128 + tx * 8 + j;
            float val = acc[i][j] + bias[c];
            int which = c / 768;
            int rem = c - which * 768;
            int h = rem >> 6, d = rem & 63;
            float* dst = (which == 0) ? qws : (which == 1) ? kws : vws;
            dst[((size_t)(bb * NHEADS + h) * SEQ + nn) * HD + d] = val;
        }
    }
}

__global__ __launch_bounds__(256)
void proj_gemm(const float* __restrict__ A, const float* __restrict__ W,
               const float* __restrict__ bias, float* __restrict__ C)
{
    const int K  = EMBED;  // 768
    const int Nn = EMBED;  // 768
    const int bm = blockIdx.y; // 0..127
    const int bn = blockIdx.x; // 0..5
    const int t  = threadIdx.x;

    __shared__ float As[8][128];
    __shared__ float Bs[8][128];

    float acc[8][8];
#pragma unroll
    for (int i = 0; i < 8; i++)
#pragma unroll
        for (int j = 0; j < 8; j++) acc[i][j] = 0.f;

    const int rowA = bm * 128 + (t >> 1);
    const int kA   = (t & 1) * 4;
    const int rowB = t >> 5;
    const int colB = bn * 128 + (t & 31) * 4;
    const int ty = t >> 4, tx = t & 15;

    for (int k0 = 0; k0 < K; k0 += 8) {
        float4 a = *(const float4*)&A[(size_t)rowA * K + k0 + kA];
        float4 b = *(const float4*)&W[(size_t)(k0 + rowB) * Nn + colB];
        As[kA + 0][t >> 1] = a.x;
        As[kA + 1][t >> 1] = a.y;
        As[kA + 2][t >> 1] = a.z;
        As[kA + 3][t >> 1] = a.w;
        *(float4*)&Bs[rowB][(t & 31) * 4] = b;
        __syncthreads();
#pragma unroll
        for (int kk = 0; kk < 8; kk++) {
            float4 a0 = *(const float4*)&As[kk][ty * 8];
            float4 a1 = *(const float4*)&As[kk][ty * 8 + 4];
            float4 b0 = *(const float4*)&Bs[kk][tx * 8];
            float4 b1 = *(const float4*)&Bs[kk][tx * 8 + 4];
            float av[8] = {a0.x, a0.y, a0.z, a0.w, a1.x, a1.y, a1.z, a1.w};
            float bv[8] = {b0.x, b0.y, b0.z, b0.w, b1.x, b1.y, b1.z, b1.w};
#pragma unroll
            for (int i = 0; i < 8; i++)
#pragma unroll
                for (int j = 0; j < 8; j++) acc[i][j] = fmaf(av[i], bv[j], acc[i][j]);
        }
        __syncthreads();
    }

#pragma unroll
    for (int i = 0; i < 8; i++) {
        int rr = bm * 128 + ty * 8 + i;
#pragma unroll
        for (int j = 0; j < 8; j++) {
            int c = bn * 128 + tx * 8 + j;
            C[(size_t)rr * Nn + c] = acc[i][j] + bias[c];
        }
    }
}

// ---------------------------------------------------------------------------
// Flash attention, fp32. One block = (b,h) x 64 q-rows. 256 threads.
// Thread t: row r = t>>2 of tile, quad-lane g = t&3 owns 16 k-cols / 16 d-cols.
// ---------------------------------------------------------------------------

__global__ __launch_bounds__(256)
void attn_kernel(const float* __restrict__ qws, const float* __restrict__ kws,
                 const float* __restrict__ vws, float* __restrict__ ows)
{
    const int bh = blockIdx.y;  // 0..191
    const int qt = blockIdx.x;  // 0..15
    const int t  = threadIdx.x;
    const int r  = t >> 2;      // 0..63
    const int g  = t & 3;       // 0..3

    __shared__ float qs[64][68];
    __shared__ float ks[64][68];
    __shared__ float vs[64][68];
    __shared__ float ps[64][68];

    const float* qbase = qws + (size_t)bh * SEQ * HD;
    const float* kbase = kws + (size_t)bh * SEQ * HD;
    const float* vbase = vws + (size_t)bh * SEQ * HD;

    // load q tile: thread loads 16 consecutive floats of one row
    {
        const int row = t >> 2;
        const int d0  = (t & 3) * 16;
        const float* src = qbase + (size_t)(qt * 64 + row) * HD + d0;
#pragma unroll
        for (int i = 0; i < 4; i++) {
            float4 v = *(const float4*)(src + i * 4);
            *(float4*)&qs[row][d0 + i * 4] = v;
        }
    }

    float m = -INFINITY, l = 0.f;
    float o[16];
#pragma unroll
    for (int i = 0; i < 16; i++) o[i] = 0.f;

    for (int kt = 0; kt < 16; ++kt) {
        __syncthreads();   // previous iteration's PV reads of ks/vs done
        {
            const int row = t >> 2;
            const int d0  = (t & 3) * 16;
            const float* srck = kbase + (size_t)(kt * 64 + row) * HD + d0;
            const float* srcv = vbase + (size_t)(kt * 64 + row) * HD + d0;
#pragma unroll
            for (int i = 0; i < 4; i++) {
                float4 kv = *(const float4*)(srck + i * 4);
                float4 vv = *(const float4*)(srcv + i * 4);
                *(float4*)&ks[row][d0 + i * 4] = kv;
                *(float4*)&vs[row][d0 + i * 4] = vv;
            }
        }
        __syncthreads();

        // scores for my 16 k-columns
        float s[16];
#pragma unroll
        for (int kk = 0; kk < 16; kk++) {
            const int k = g * 16 + kk;
            float sum = 0.f;
#pragma unroll
            for (int d = 0; d < 64; d += 4) {
                float4 qv = *(const float4*)&qs[r][d];
                float4 kv = *(const float4*)&ks[k][d];
                sum = fmaf(qv.x, kv.x, sum);
                sum = fmaf(qv.y, kv.y, sum);
                sum = fmaf(qv.z, kv.z, sum);
                sum = fmaf(qv.w, kv.w, sum);
            }
            s[kk] = sum * ATTN_SCALE;
        }

        float tmax = s[0];
#pragma unroll
        for (int kk = 1; kk < 16; kk++) tmax = fmaxf(tmax, s[kk]);
        tmax = fmaxf(tmax, __shfl_xor(tmax, 1, 64));
        tmax = fmaxf(tmax, __shfl_xor(tmax, 2, 64));
        float mnew = fmaxf(m, tmax);
        float alpha = __expf(m - mnew);   // exp(-inf)=0 on first tile
        float psum = 0.f;
#pragma unroll
        for (int kk = 0; kk < 16; kk++) {
            s[kk] = __expf(s[kk] - mnew);
            psum += s[kk];
        }
        psum += __shfl_xor(psum, 1, 64);
        psum += __shfl_xor(psum, 2, 64);
        l = l * alpha + psum;
        m = mnew;
#pragma unroll
        for (int i = 0; i < 16; i++) o[i] *= alpha;
#pragma unroll
        for (int kk = 0; kk < 16; kk++) ps[r][g * 16 + kk] = s[kk];
        __syncthreads();

        // PV: o[dd] += sum_k p[r][k] * v[k][g*16+dd]
#pragma unroll 4
        for (int k = 0; k < 64; k++) {
            float p = ps[r][k];
            float4 v0 = *(const float4*)&vs[k][g * 16 + 0];
            float4 v1 = *(const float4*)&vs[k][g * 16 + 4];
            float4 v2 = *(const float4*)&vs[k][g * 16 + 8];
            float4 v3 = *(const float4*)&vs[k][g * 16 + 12];
            o[0]  = fmaf(p, v0.x, o[0]);  o[1]  = fmaf(p, v0.y, o[1]);
            o[2]  = fmaf(p, v0.z, o[2]);  o[3]  = fmaf(p, v0.w, o[3]);
            o[4]  = fmaf(p, v1.x, o[4]);  o[5]  = fmaf(p, v1.y, o[5]);
            o[6]  = fmaf(p, v1.z, o[6]);  o[7]  = fmaf(p, v1.w, o[7]);
            o[8]  = fmaf(p, v2.x, o[8]);  o[9]  = fmaf(p, v2.y, o[9]);
            o[10] = fmaf(p, v2.z, o[10]); o[11] = fmaf(p, v2.w, o[11]);
            o[12] = fmaf(p, v3.x, o[12]); o[13] = fmaf(p, v3.y, o[13]);
            o[14] = fmaf(p, v3.z, o[14]); o[15] = fmaf(p, v3.w, o[15]);
        }
    }

    const float inv = 1.f / l;
    const int b = bh / NHEADS, h = bh % NHEADS;
    const int n = qt * 64 + r;
    float* dst = ows + ((size_t)(b * SEQ + n) * NHEADS + h) * HD + g * 16;
#pragma unroll
    for (int i = 0; i < 16; i++) dst[i] = o[i] * inv;
}

// ---------------------------------------------------------------------------

extern "C" void kernel_launch(void* const* d_in, const int* in_sizes, int n_in,
                              void* d_out, int out_size, void* d_ws, size_t ws_size,
                              hipStream_t stream)
{
    const float* x      = (const float*)d_in[0];
    const float* W_qkv  = (const float*)d_in[1];
    const float* b_qkv  = (const float*)d_in[2];
    const float* W_proj = (const float*)d_in[3];
    const float* b_proj = (const float*)d_in[4];
    float* out = (float*)d_out;

    const size_t per = (size_t)BATCH * NHEADS * SEQ * HD;  // 12,582,912 floats
    float* ws     = (float*)d_ws;
    float* q_ws   = ws;
    float* k_ws   = q_ws + per;
    float* v_ws   = k_ws + per;
    float* a_ws   = v_ws + per;   // attention output [B,N,768]

    dim3 g1(3 * EMBED / 128, BATCH * SEQ / 128);   // (18, 128)
    qkv_gemm<<<g1, 256, 0, stream>>>(x, W_qkv, b_qkv, q_ws, k_ws, v_ws);

    dim3 g2(SEQ / 64, BATCH * NHEADS);             // (16, 192)
    attn_kernel<<<g2, 256, 0, stream>>>(q_ws, k_ws, v_ws, a_ws);

    dim3 g3(EMBED / 128, BATCH * SEQ / 128);       // (6, 128)
    proj_gemm<<<g3, 256, 0, stream>>>(a_ws, W_proj, b_proj, out);
}

// Round 2
// 572.533 us; speedup vs baseline: 5.3276x; 5.3276x over previous
//
#include <hip/hip_runtime.h>
#include <math.h>

typedef _Float16 f16;
typedef _Float16 f16x8 __attribute__((ext_vector_type(8)));
typedef _Float16 f16x4 __attribute__((ext_vector_type(4)));
typedef float    f32x4 __attribute__((ext_vector_type(4)));

#define AS1 __attribute__((address_space(1)))
#define AS3 __attribute__((address_space(3)))

__device__ __forceinline__ void gload16(const void* g, void* l) {
    __builtin_amdgcn_global_load_lds((const AS1 void*)g, (AS3 void*)l, 16, 0, 0);
}

// ---------------------------------------------------------------------------
// cast x fp32 -> f16
// ---------------------------------------------------------------------------
__global__ __launch_bounds__(256) void cast_x_k(const float* __restrict__ in,
                                                f16* __restrict__ out, int n8)
{
    int i = blockIdx.x * 256 + threadIdx.x;
    const int stride = gridDim.x * 256;
    const float4* in4 = (const float4*)in;
    f16x8* o8 = (f16x8*)out;
    for (; i < n8; i += stride) {
        float4 a = in4[2 * i], b = in4[2 * i + 1];
        f16x8 o = {(f16)a.x, (f16)a.y, (f16)a.z, (f16)a.w,
                   (f16)b.x, (f16)b.y, (f16)b.z, (f16)b.w};
        o8[i] = o;
    }
}

// ---------------------------------------------------------------------------
// cast + transpose W [K][N] fp32 -> WT [N][K] f16
// ---------------------------------------------------------------------------
__global__ __launch_bounds__(256) void castT_k(const float* __restrict__ W,
                                               f16* __restrict__ WT, int K, int N)
{
    __shared__ float tile[32][33];
    const int k0 = blockIdx.y * 32, n0 = blockIdx.x * 32;
    const int t = threadIdx.x;
    const int r = t >> 3, cq = t & 7;
    float4 v = *(const float4*)&W[(size_t)(k0 + r) * N + n0 + cq * 4];
    tile[r][cq * 4 + 0] = v.x; tile[r][cq * 4 + 1] = v.y;
    tile[r][cq * 4 + 2] = v.z; tile[r][cq * 4 + 3] = v.w;
    __syncthreads();
    f16x4 pk = {(f16)tile[cq * 4 + 0][r], (f16)tile[cq * 4 + 1][r],
                (f16)tile[cq * 4 + 2][r], (f16)tile[cq * 4 + 3][r]};
    *(f16x4*)&WT[(size_t)(n0 + r) * K + k0 + cq * 4] = pk;
}

// ---------------------------------------------------------------------------
// transpose V [bh][1024][64] f16 -> VT [bh][64][1024] f16
// ---------------------------------------------------------------------------
__global__ __launch_bounds__(256) void vtrans_k(const f16* __restrict__ V,
                                                f16* __restrict__ VT)
{
    __shared__ __align__(16) f16 tile[64][72];   // 144B rows (16B-aligned)
    const int bh = blockIdx.y, tt = blockIdx.x;
    const int t = threadIdx.x;
    const size_t base = (size_t)bh * 1024 * 64;
    {
        int tok = t >> 2, d0 = (t & 3) * 16;
        const f16* src = V + base + (size_t)(tt * 64 + tok) * 64 + d0;
        *(f16x8*)&tile[tok][d0]     = *(const f16x8*)src;
        *(f16x8*)&tile[tok][d0 + 8] = *(const f16x8*)(src + 8);
    }
    __syncthreads();
    {
        int d = t >> 2, ck = t & 3;
        f16 tmp[16];
#pragma unroll
        for (int j = 0; j < 16; ++j) tmp[j] = tile[ck * 16 + j][d];
        f16* dst = VT + base + (size_t)d * 1024 + tt * 64 + ck * 16;
        *(f16x8*)dst       = *(f16x8*)&tmp[0];
        *(f16x8*)(dst + 8) = *(f16x8*)&tmp[8];
    }
}

// ---------------------------------------------------------------------------
// f16 MFMA GEMM, 128x128 tile, BK=64, 4 waves (2x2), 16x16x32 frags.
// A [M][768] f16 row-major, BT [N][768] f16 (pre-transposed B).
// LDS linear, source-swizzled staging (chunk ^= row&7); reads undo the XOR.
// ---------------------------------------------------------------------------
#define GEMM_MAIN(APTR, BTPTR)                                                   \
    __shared__ __align__(16) f16 As[128 * 64];                                   \
    __shared__ __align__(16) f16 Bs[128 * 64];                                   \
    const int t = threadIdx.x, lid = t & 63, wid = t >> 6;                       \
    const int wr = wid >> 1, wc = wid & 1;                                       \
    const int bm = blockIdx.y, bn = blockIdx.x;                                  \
    f32x4 acc[4][4] = {};                                                        \
    const int srow8 = lid >> 3;                                                  \
    const int sc = (lid & 7) ^ srow8;                                            \
    const f16* aG = (APTR) + (size_t)(bm * 128 + wid * 32 + srow8) * 768 + sc * 8;\
    const f16* bG = (BTPTR) + (size_t)(bn * 128 + wid * 32 + srow8) * 768 + sc * 8;\
    f16* ldsA = As + wid * 32 * 64;                                              \
    f16* ldsB = Bs + wid * 32 * 64;                                              \
    for (int k0 = 0; k0 < 768; k0 += 64) {                                       \
        __syncthreads();                                                         \
        _Pragma("unroll")                                                        \
        for (int c = 0; c < 4; ++c) {                                            \
            gload16(aG + c * 8 * 768 + k0, ldsA + c * 8 * 64);                   \
            gload16(bG + c * 8 * 768 + k0, ldsB + c * 8 * 64);                   \
        }                                                                        \
        __syncthreads();                                                         \
        _Pragma("unroll")                                                        \
        for (int kh = 0; kh < 2; ++kh) {                                         \
            f16x8 af[4], bf[4];                                                  \
            _Pragma("unroll")                                                    \
            for (int m = 0; m < 4; ++m) {                                        \
                int row = wr * 64 + m * 16 + (lid & 15);                         \
                int slot = (kh * 4 + (lid >> 4)) ^ (row & 7);                    \
                af[m] = *(const f16x8*)&As[row * 64 + slot * 8];                 \
                int col = wc * 64 + m * 16 + (lid & 15);                         \
                int slotb = (kh * 4 + (lid >> 4)) ^ (col & 7);                   \
                bf[m] = *(const f16x8*)&Bs[col * 64 + slotb * 8];                \
            }                                                                    \
            _Pragma("unroll")                                                    \
            for (int m = 0; m < 4; ++m)                                          \
                _Pragma("unroll")                                                \
                for (int n = 0; n < 4; ++n)                                      \
                    acc[m][n] = __builtin_amdgcn_mfma_f32_16x16x32_f16(          \
                        af[m], bf[n], acc[m][n], 0, 0, 0);                       \
        }                                                                        \
    }

__global__ __launch_bounds__(256)
void qkv_gemm16(const f16* __restrict__ A, const f16* __restrict__ BT,
                const float* __restrict__ bias,
                f16* __restrict__ qws, f16* __restrict__ kws, f16* __restrict__ vws)
{
    GEMM_MAIN(A, BT)
    const int g = lid >> 4, cl = lid & 15;
#pragma unroll
    for (int m = 0; m < 4; ++m) {
        int rbase = bm * 128 + wr * 64 + m * 16 + g * 4;
#pragma unroll
        for (int n = 0; n < 4; ++n) {
            int cg = bn * 128 + wc * 64 + n * 16 + cl;
            float bb = bias[cg];
            int which = cg / 768;
            int rem = cg - which * 768;
            int h = rem >> 6, d = rem & 63;
            f16* dst = (which == 0) ? qws : (which == 1) ? kws : vws;
            float scl = (which == 0) ? 0.125f : 1.0f;   // fold attn scale into Q
#pragma unroll
            for (int r = 0; r < 4; ++r) {
                int row = rbase + r;
                int b = row >> 10, tok = row & 1023;
                dst[((size_t)(b * 12 + h) * 1024 + tok) * 64 + d] =
                    (f16)((acc[m][n][r] + bb) * scl);
            }
        }
    }
}

__global__ __launch_bounds__(256)
void proj_gemm16(const f16* __restrict__ A, const f16* __restrict__ BT,
                 const float* __restrict__ bias, float* __restrict__ C)
{
    GEMM_MAIN(A, BT)
    const int g = lid >> 4, cl = lid & 15;
#pragma unroll
    for (int m = 0; m < 4; ++m) {
        int rbase = bm * 128 + wr * 64 + m * 16 + g * 4;
#pragma unroll
        for (int n = 0; n < 4; ++n) {
            int cg = bn * 128 + wc * 64 + n * 16 + cl;
            float bb = bias[cg];
#pragma unroll
            for (int r = 0; r < 4; ++r)
                C[(size_t)(rbase + r) * 768 + cg] = acc[m][n][r] + bb;
        }
    }
}

// ---------------------------------------------------------------------------
// MFMA flash attention. 4 independent waves/block; wave = 16 q-rows.
// Swapped QK^T: S^T = mfma(K, Q) -> lane owns q-row (lid&15) across 16 keys.
// P bounced via per-wave 2KB LDS (XOR-swizzled); K and VT read direct (L2).
// ---------------------------------------------------------------------------
__global__ __launch_bounds__(256)
void attn16(const f16* __restrict__ Q, const f16* __restrict__ K,
            const f16* __restrict__ VT, f16* __restrict__ AO)
{
    __shared__ __align__(16) f16 plds[4][16 * 64];
    const int t = threadIdx.x, lid = t & 63, wid = t >> 6;
    const int bh = blockIdx.y, qt = blockIdx.x;
    const int g = lid >> 4, c = lid & 15;
    const size_t hb = (size_t)bh * (1024 * 64);
    const int q0 = qt * 64 + wid * 16;

    const f16* qrow = Q + hb + (size_t)(q0 + c) * 64;
    const f16x8 qf0 = *(const f16x8*)(qrow + g * 8);
    const f16x8 qf1 = *(const f16x8*)(qrow + 32 + g * 8);

    f32x4 o[4] = {};
    float mrun = -INFINITY, lrun = 0.f;
    f16* myp = &plds[wid][0];

    for (int kt = 0; kt < 16; ++kt) {
        const f16* kb = K + hb + (size_t)(kt * 64) * 64;
        f32x4 s[4] = {};
#pragma unroll
        for (int m = 0; m < 4; ++m) {
            const f16* krow = kb + (size_t)(m * 16 + c) * 64;
            f16x8 k0f = *(const f16x8*)(krow + g * 8);
            f16x8 k1f = *(const f16x8*)(krow + 32 + g * 8);
            s[m] = __builtin_amdgcn_mfma_f32_16x16x32_f16(k0f, qf0, s[m], 0, 0, 0);
            s[m] = __builtin_amdgcn_mfma_f32_16x16x32_f16(k1f, qf1, s[m], 0, 0, 0);
        }
        // online softmax for q-row (c); union over 4 g-lanes covers 64 keys
        float tmax = s[0][0];
#pragma unroll
        for (int m = 0; m < 4; ++m)
#pragma unroll
            for (int r = 0; r < 4; ++r) tmax = fmaxf(tmax, s[m][r]);
        tmax = fmaxf(tmax, __shfl_xor(tmax, 16));
        tmax = fmaxf(tmax, __shfl_xor(tmax, 32));
        float mnew = fmaxf(mrun, tmax);
        float al = __expf(mrun - mnew);     // first tile: exp(-inf)=0
        float ps = 0.f;
        float pe[4][4];
#pragma unroll
        for (int m = 0; m < 4; ++m)
#pragma unroll
            for (int r = 0; r < 4; ++r) {
                float p = __expf(s[m][r] - mnew);
                pe[m][r] = p; ps += p;
            }
        ps += __shfl_xor(ps, 16);
        ps += __shfl_xor(ps, 32);
        lrun = lrun * al + ps;
        mrun = mnew;
        // stage P[qrow=c][keys m*16+g*4+0..3] -> swizzled LDS (8B writes)
#pragma unroll
        for (int m = 0; m < 4; ++m) {
            f16x4 pk = {(f16)pe[m][0], (f16)pe[m][1], (f16)pe[m][2], (f16)pe[m][3]};
            int slot = (2 * m + (g >> 1)) ^ (c & 7);
            *(f16x4*)&myp[c * 64 + slot * 8 + (g & 1) * 4] = pk;
        }
        // rescale O rows (rows g*4+r; alpha lives at lane (g*4+r))
        float al4[4];
#pragma unroll
        for (int r = 0; r < 4; ++r) al4[r] = __shfl(al, g * 4 + r);
#pragma unroll
        for (int n = 0; n < 4; ++n) {
            o[n][0] *= al4[0]; o[n][1] *= al4[1];
            o[n][2] *= al4[2]; o[n][3] *= al4[3];
        }
        // PV: A-frag from swizzled LDS, B-frag direct from VT
        f16x8 pa[2];
#pragma unroll
        for (int kh = 0; kh < 2; ++kh) {
            int slot = (kh * 4 + g) ^ (c & 7);
            pa[kh] = *(const f16x8*)&myp[c * 64 + slot * 8];
        }
        const f16* vb = VT + hb + kt * 64;
#pragma unroll
        for (int kh = 0; kh < 2; ++kh)
#pragma unroll
            for (int n = 0; n < 4; ++n) {
                f16x8 vf = *(const f16x8*)&vb[(size_t)(n * 16 + c) * 1024 + kh * 32 + g * 8];
                o[n] = __builtin_amdgcn_mfma_f32_16x16x32_f16(pa[kh], vf, o[n], 0, 0, 0);
            }
    }
    float il = 1.0f / lrun;
    float il4[4];
#pragma unroll
    for (int r = 0; r < 4; ++r) il4[r] = __shfl(il, g * 4 + r);
    const int b = bh / 12, h = bh - b * 12;
#pragma unroll
    for (int n = 0; n < 4; ++n)
#pragma unroll
        for (int r = 0; r < 4; ++r) {
            int tok = q0 + g * 4 + r;
            AO[(size_t)(b * 1024 + tok) * 768 + h * 64 + n * 16 + c] =
                (f16)(o[n][r] * il4[r]);
        }
}

// ---------------------------------------------------------------------------

extern "C" void kernel_launch(void* const* d_in, const int* in_sizes, int n_in,
                              void* d_out, int out_size, void* d_ws, size_t ws_size,
                              hipStream_t stream)
{
    const float* x      = (const float*)d_in[0];
    const float* W_qkv  = (const float*)d_in[1];
    const float* b_qkv  = (const float*)d_in[2];
    const float* W_proj = (const float*)d_in[3];
    const float* b_proj = (const float*)d_in[4];
    float* out = (float*)d_out;

    const size_t per = (size_t)16 * 1024 * 768;   // 12,582,912
    f16* x16    = (f16*)d_ws;
    f16* wqkvT  = x16 + per;
    f16* wprojT = wqkvT + (size_t)768 * 2304;
    f16* qws    = wprojT + (size_t)768 * 768;
    f16* kws    = qws + per;
    f16* vws    = kws + per;
    f16* vt     = vws + per;
    f16* aws    = vt + per;

    cast_x_k<<<3072, 256, 0, stream>>>(x, x16, (int)(per / 8));
    castT_k<<<dim3(2304 / 32, 768 / 32), 256, 0, stream>>>(W_qkv, wqkvT, 768, 2304);
    castT_k<<<dim3(768 / 32, 768 / 32), 256, 0, stream>>>(W_proj, wprojT, 768, 768);
    qkv_gemm16<<<dim3(18, 128), 256, 0, stream>>>(x16, wqkvT, b_qkv, qws, kws, vws);
    vtrans_k<<<dim3(16, 192), 256, 0, stream>>>(vws, vt);
    attn16<<<dim3(16, 192), 256, 0, stream>>>(qws, kws, vt, aws);
    proj_gemm16<<<dim3(6, 128), 256, 0, stream>>>(aws, wprojT, b_proj, out);
}

// Round 3
// 341.874 us; speedup vs baseline: 8.9220x; 1.6747x over previous
//
#include <hip/hip_runtime.h>
#include <math.h>

typedef _Float16 f16;
typedef _Float16 f16x8 __attribute__((ext_vector_type(8)));
typedef _Float16 f16x4 __attribute__((ext_vector_type(4)));
typedef float    f32x4 __attribute__((ext_vector_type(4)));

#define AS1 __attribute__((address_space(1)))
#define AS3 __attribute__((address_space(3)))

__device__ __forceinline__ void gload16(const void* g, void* l) {
    __builtin_amdgcn_global_load_lds((const AS1 void*)g, (AS3 void*)l, 16, 0, 0);
}

// ---------------------------------------------------------------------------
// cast x fp32 -> f16
// ---------------------------------------------------------------------------
__global__ __launch_bounds__(256) void cast_x_k(const float* __restrict__ in,
                                                f16* __restrict__ out, int n8)
{
    int i = blockIdx.x * 256 + threadIdx.x;
    const int stride = gridDim.x * 256;
    const float4* in4 = (const float4*)in;
    f16x8* o8 = (f16x8*)out;
    for (; i < n8; i += stride) {
        float4 a = in4[2 * i], b = in4[2 * i + 1];
        f16x8 o = {(f16)a.x, (f16)a.y, (f16)a.z, (f16)a.w,
                   (f16)b.x, (f16)b.y, (f16)b.z, (f16)b.w};
        o8[i] = o;
    }
}

// ---------------------------------------------------------------------------
// cast + transpose W [K][N] fp32 -> WT [N][K] f16
// ---------------------------------------------------------------------------
__global__ __launch_bounds__(256) void castT_k(const float* __restrict__ W,
                                               f16* __restrict__ WT, int K, int N)
{
    __shared__ float tile[32][33];
    const int k0 = blockIdx.y * 32, n0 = blockIdx.x * 32;
    const int t = threadIdx.x;
    const int r = t >> 3, cq = t & 7;
    float4 v = *(const float4*)&W[(size_t)(k0 + r) * N + n0 + cq * 4];
    tile[r][cq * 4 + 0] = v.x; tile[r][cq * 4 + 1] = v.y;
    tile[r][cq * 4 + 2] = v.z; tile[r][cq * 4 + 3] = v.w;
    __syncthreads();
    f16x4 pk = {(f16)tile[cq * 4 + 0][r], (f16)tile[cq * 4 + 1][r],
                (f16)tile[cq * 4 + 2][r], (f16)tile[cq * 4 + 3][r]};
    *(f16x4*)&WT[(size_t)(n0 + r) * K + k0 + cq * 4] = pk;
}

// ---------------------------------------------------------------------------
// transpose V [bh][1024][64] f16 -> VT [bh][64][1024] f16
// ---------------------------------------------------------------------------
__global__ __launch_bounds__(256) void vtrans_k(const f16* __restrict__ V,
                                                f16* __restrict__ VT)
{
    __shared__ __align__(16) f16 tile[64][72];   // 144B rows (16B-aligned)
    const int bh = blockIdx.y, tt = blockIdx.x;
    const int t = threadIdx.x;
    const size_t base = (size_t)bh * 1024 * 64;
    {
        int tok = t >> 2, d0 = (t & 3) * 16;
        const f16* src = V + base + (size_t)(tt * 64 + tok) * 64 + d0;
        *(f16x8*)&tile[tok][d0]     = *(const f16x8*)src;
        *(f16x8*)&tile[tok][d0 + 8] = *(const f16x8*)(src + 8);
    }
    __syncthreads();
    {
        int d = t >> 2, ck = t & 3;
        f16 tmp[16];
#pragma unroll
        for (int j = 0; j < 16; ++j) tmp[j] = tile[ck * 16 + j][d];
        f16* dst = VT + base + (size_t)d * 1024 + tt * 64 + ck * 16;
        *(f16x8*)dst       = *(f16x8*)&tmp[0];
        *(f16x8*)(dst + 8) = *(f16x8*)&tmp[8];
    }
}

// ---------------------------------------------------------------------------
// f16 MFMA GEMM, 128x128 tile, BK=64, 4 waves (2x2), 16x16x32 frags.
// A [M][768] f16 row-major, BT [N][768] f16 (pre-transposed B).
// LDS linear, source-swizzled staging (chunk ^= row&7); reads undo the XOR.
// ---------------------------------------------------------------------------
#define GEMM_MAIN(APTR, BTPTR)                                                   \
    __shared__ __align__(16) f16 As[128 * 64];                                   \
    __shared__ __align__(16) f16 Bs[128 * 64];                                   \
    const int t = threadIdx.x, lid = t & 63, wid = t >> 6;                       \
    const int wr = wid >> 1, wc = wid & 1;                                       \
    const int bm = blockIdx.y, bn = blockIdx.x;                                  \
    f32x4 acc[4][4] = {};                                                        \
    const int srow8 = lid >> 3;                                                  \
    const int sc = (lid & 7) ^ srow8;                                            \
    const f16* aG = (APTR) + (size_t)(bm * 128 + wid * 32 + srow8) * 768 + sc * 8;\
    const f16* bG = (BTPTR) + (size_t)(bn * 128 + wid * 32 + srow8) * 768 + sc * 8;\
    f16* ldsA = As + wid * 32 * 64;                                              \
    f16* ldsB = Bs + wid * 32 * 64;                                              \
    for (int k0 = 0; k0 < 768; k0 += 64) {                                       \
        __syncthreads();                                                         \
        _Pragma("unroll")                                                        \
        for (int c = 0; c < 4; ++c) {                                            \
            gload16(aG + c * 8 * 768 + k0, ldsA + c * 8 * 64);                   \
            gload16(bG + c * 8 * 768 + k0, ldsB + c * 8 * 64);                   \
        }                                                                        \
        __syncthreads();                                                         \
        _Pragma("unroll")                                                        \
        for (int kh = 0; kh < 2; ++kh) {                                         \
            f16x8 af[4], bf[4];                                                  \
            _Pragma("unroll")                                                    \
            for (int m = 0; m < 4; ++m) {                                        \
                int row = wr * 64 + m * 16 + (lid & 15);                         \
                int slot = (kh * 4 + (lid >> 4)) ^ (row & 7);                    \
                af[m] = *(const f16x8*)&As[row * 64 + slot * 8];                 \
                int col = wc * 64 + m * 16 + (lid & 15);                         \
                int slotb = (kh * 4 + (lid >> 4)) ^ (col & 7);                   \
                bf[m] = *(const f16x8*)&Bs[col * 64 + slotb * 8];                \
            }                                                                    \
            _Pragma("unroll")                                                    \
            for (int m = 0; m < 4; ++m)                                          \
                _Pragma("unroll")                                                \
                for (int n = 0; n < 4; ++n)                                      \
                    acc[m][n] = __builtin_amdgcn_mfma_f32_16x16x32_f16(          \
                        af[m], bf[n], acc[m][n], 0, 0, 0);                       \
        }                                                                        \
    }

__global__ __launch_bounds__(256)
void qkv_gemm16(const f16* __restrict__ A, const f16* __restrict__ BT,
                const float* __restrict__ bias,
                f16* __restrict__ qws, f16* __restrict__ kws, f16* __restrict__ vws)
{
    GEMM_MAIN(A, BT)
    const int g = lid >> 4, cl = lid & 15;
#pragma unroll
    for (int m = 0; m < 4; ++m) {
        int rbase = bm * 128 + wr * 64 + m * 16 + g * 4;
#pragma unroll
        for (int n = 0; n < 4; ++n) {
            int cg = bn * 128 + wc * 64 + n * 16 + cl;
            float bb = bias[cg];
            int which = cg / 768;
            int rem = cg - which * 768;
            int h = rem >> 6, d = rem & 63;
            f16* dst = (which == 0) ? qws : (which == 1) ? kws : vws;
            float scl = (which == 0) ? 0.125f : 1.0f;   // fold attn scale into Q
#pragma unroll
            for (int r = 0; r < 4; ++r) {
                int row = rbase + r;
                int b = row >> 10, tok = row & 1023;
                dst[((size_t)(b * 12 + h) * 1024 + tok) * 64 + d] =
                    (f16)((acc[m][n][r] + bb) * scl);
            }
        }
    }
}

__global__ __launch_bounds__(256)
void proj_gemm16(const f16* __restrict__ A, const f16* __restrict__ BT,
                 const float* __restrict__ bias, float* __restrict__ C)
{
    GEMM_MAIN(A, BT)
    const int g = lid >> 4, cl = lid & 15;
#pragma unroll
    for (int m = 0; m < 4; ++m) {
        int rbase = bm * 128 + wr * 64 + m * 16 + g * 4;
#pragma unroll
        for (int n = 0; n < 4; ++n) {
            int cg = bn * 128 + wc * 64 + n * 16 + cl;
            float bb = bias[cg];
#pragma unroll
            for (int r = 0; r < 4; ++r)
                C[(size_t)(rbase + r) * 768 + cg] = acc[m][n][r] + bb;
        }
    }
}

// ---------------------------------------------------------------------------
// MFMA flash attention with LDS-staged, double-buffered K/V tiles.
// Block = 64 q-rows of one (b,h); 4 waves, wave = 16 q-rows.
// Swapped QK^T: S^T = mfma(K, Q) -> lane owns q-row (lid&15) across 16 keys.
// K tile [64 keys][64 d], V tile [64 d][64 tok] staged via global_load_lds
// (linear LDS dest, XOR-pre-swizzled global source: chunk ^= row&7).
// XCD-aware block swizzle groups the 16 qt-blocks of one head per XCD L2.
// ---------------------------------------------------------------------------
__global__ __launch_bounds__(256)
void attn16(const f16* __restrict__ Q, const f16* __restrict__ K,
            const f16* __restrict__ VT, f16* __restrict__ AO)
{
    __shared__ __align__(16) f16 kbuf[2][64 * 64];
    __shared__ __align__(16) f16 vbuf[2][64 * 64];
    __shared__ __align__(16) f16 plds[4][16 * 64];

    const int t = threadIdx.x, lid = t & 63, wid = t >> 6;
    // XCD swizzle: 3072 blocks, 8 XCDs, 384/XCD; contiguous logical ids
    // (16 qt of a head are consecutive) land on one XCD.
    const int phys = blockIdx.y * gridDim.x + blockIdx.x;
    const int logical = (phys & 7) * 384 + (phys >> 3);
    const int bh = logical >> 4, qt = logical & 15;

    const int g = lid >> 4, c = lid & 15;
    const size_t hb = (size_t)bh * (1024 * 64);
    const int q0 = qt * 64 + wid * 16;

    const f16* qrow = Q + hb + (size_t)(q0 + c) * 64;
    const f16x8 qf0 = *(const f16x8*)(qrow + g * 8);
    const f16x8 qf1 = *(const f16x8*)(qrow + 32 + g * 8);

    // staging geometry: wave w stages rows [w*16, w*16+16) in 2 issues of 8 rows
    const int srow   = wid * 16 + (lid >> 3);              // + c2*8
    const int schunk = ((lid & 7) ^ (lid >> 3)) * 8;       // pre-swizzled source chunk

#define ATTN_STAGE(BUF, KT)                                                      \
    {                                                                            \
        const f16* kb_ = K + hb + (size_t)((KT) * 64) * 64;                      \
        const f16* vb_ = VT + hb + (KT) * 64;                                    \
        _Pragma("unroll")                                                        \
        for (int c2 = 0; c2 < 2; ++c2) {                                         \
            gload16(kb_ + (size_t)(srow + c2 * 8) * 64 + schunk,                 \
                    &kbuf[BUF][wid * 1024 + c2 * 512]);                          \
            gload16(vb_ + (size_t)(srow + c2 * 8) * 1024 + schunk,               \
                    &vbuf[BUF][wid * 1024 + c2 * 512]);                          \
        }                                                                        \
    }

    f32x4 o[4] = {};
    float mrun = -INFINITY, lrun = 0.f;
    f16* myp = &plds[wid][0];

    ATTN_STAGE(0, 0)
    __syncthreads();

    int cur = 0;
    for (int kt = 0; kt < 16; ++kt) {
        if (kt < 15) ATTN_STAGE(cur ^ 1, kt + 1)

        const f16* kcur = &kbuf[cur][0];
        const f16* vcur = &vbuf[cur][0];
        const int sw = c & 7;

        f32x4 s[4] = {};
#pragma unroll
        for (int m = 0; m < 4; ++m) {
            const int row = m * 16 + c;
            f16x8 k0f = *(const f16x8*)&kcur[row * 64 + ((g) ^ sw) * 8];
            f16x8 k1f = *(const f16x8*)&kcur[row * 64 + ((4 + g) ^ sw) * 8];
            s[m] = __builtin_amdgcn_mfma_f32_16x16x32_f16(k0f, qf0, s[m], 0, 0, 0);
            s[m] = __builtin_amdgcn_mfma_f32_16x16x32_f16(k1f, qf1, s[m], 0, 0, 0);
        }
        // online softmax for q-row (c); union over 4 g-lanes covers 64 keys
        float tmax = s[0][0];
#pragma unroll
        for (int m = 0; m < 4; ++m)
#pragma unroll
            for (int r = 0; r < 4; ++r) tmax = fmaxf(tmax, s[m][r]);
        tmax = fmaxf(tmax, __shfl_xor(tmax, 16));
        tmax = fmaxf(tmax, __shfl_xor(tmax, 32));
        float mnew = fmaxf(mrun, tmax);
        float al = __expf(mrun - mnew);     // first tile: exp(-inf)=0
        float ps = 0.f;
        float pe[4][4];
#pragma unroll
        for (int m = 0; m < 4; ++m)
#pragma unroll
            for (int r = 0; r < 4; ++r) {
                float p = __expf(s[m][r] - mnew);
                pe[m][r] = p; ps += p;
            }
        ps += __shfl_xor(ps, 16);
        ps += __shfl_xor(ps, 32);
        lrun = lrun * al + ps;
        mrun = mnew;
        // stage P[qrow=c][keys m*16+g*4+0..3] -> swizzled per-wave LDS (8B writes)
#pragma unroll
        for (int m = 0; m < 4; ++m) {
            f16x4 pk = {(f16)pe[m][0], (f16)pe[m][1], (f16)pe[m][2], (f16)pe[m][3]};
            int slot = (2 * m + (g >> 1)) ^ sw;
            *(f16x4*)&myp[c * 64 + slot * 8 + (g & 1) * 4] = pk;
        }
        // rescale O rows (rows g*4+r; alpha lives at lane (g*4+r))
        float al4[4];
#pragma unroll
        for (int r = 0; r < 4; ++r) al4[r] = __shfl(al, g * 4 + r);
#pragma unroll
        for (int n = 0; n < 4; ++n) {
            o[n][0] *= al4[0]; o[n][1] *= al4[1];
            o[n][2] *= al4[2]; o[n][3] *= al4[3];
        }
        // PV: A-frag from swizzled per-wave LDS, B-frag from staged V tile
        f16x8 pa[2];
#pragma unroll
        for (int kh = 0; kh < 2; ++kh) {
            int slot = (kh * 4 + g) ^ sw;
            pa[kh] = *(const f16x8*)&myp[c * 64 + slot * 8];
        }
#pragma unroll
        for (int kh = 0; kh < 2; ++kh)
#pragma unroll
            for (int n = 0; n < 4; ++n) {
                const int row = n * 16 + c;
                f16x8 vf = *(const f16x8*)&vcur[row * 64 + ((kh * 4 + g) ^ sw) * 8];
                o[n] = __builtin_amdgcn_mfma_f32_16x16x32_f16(pa[kh], vf, o[n], 0, 0, 0);
            }

        __syncthreads();   // drains stage vmcnt + all waves done with buf[cur]
        cur ^= 1;
    }

    float il = 1.0f / lrun;
    float il4[4];
#pragma unroll
    for (int r = 0; r < 4; ++r) il4[r] = __shfl(il, g * 4 + r);
    const int b = bh / 12, h = bh - b * 12;
#pragma unroll
    for (int n = 0; n < 4; ++n)
#pragma unroll
        for (int r = 0; r < 4; ++r) {
            int tok = q0 + g * 4 + r;
            AO[(size_t)(b * 1024 + tok) * 768 + h * 64 + n * 16 + c] =
                (f16)(o[n][r] * il4[r]);
        }
}

// ---------------------------------------------------------------------------

extern "C" void kernel_launch(void* const* d_in, const int* in_sizes, int n_in,
                              void* d_out, int out_size, void* d_ws, size_t ws_size,
                              hipStream_t stream)
{
    const float* x      = (const float*)d_in[0];
    const float* W_qkv  = (const float*)d_in[1];
    const float* b_qkv  = (const float*)d_in[2];
    const float* W_proj = (const float*)d_in[3];
    const float* b_proj = (const float*)d_in[4];
    float* out = (float*)d_out;

    const size_t per = (size_t)16 * 1024 * 768;   // 12,582,912
    f16* x16    = (f16*)d_ws;
    f16* wqkvT  = x16 + per;
    f16* wprojT = wqkvT + (size_t)768 * 2304;
    f16* qws    = wprojT + (size_t)768 * 768;
    f16* kws    = qws + per;
    f16* vws    = kws + per;
    f16* vt     = vws + per;
    f16* aws    = vt + per;

    cast_x_k<<<3072, 256, 0, stream>>>(x, x16, (int)(per / 8));
    castT_k<<<dim3(2304 / 32, 768 / 32), 256, 0, stream>>>(W_qkv, wqkvT, 768, 2304);
    castT_k<<<dim3(768 / 32, 768 / 32), 256, 0, stream>>>(W_proj, wprojT, 768, 768);
    qkv_gemm16<<<dim3(18, 128), 256, 0, stream>>>(x16, wqkvT, b_qkv, qws, kws, vws);
    vtrans_k<<<dim3(16, 192), 256, 0, stream>>>(vws, vt);
    attn16<<<dim3(16, 192), 256, 0, stream>>>(qws, kws, vt, aws);
    proj_gemm16<<<dim3(6, 128), 256, 0, stream>>>(aws, wprojT, b_proj, out);
}